// Round 1
// baseline (181.988 us; speedup 1.0000x reference)
//
#include <hip/hip_runtime.h>
#include <cstdint>

typedef _Float16 half8 __attribute__((ext_vector_type(8)));
typedef float f32x4 __attribute__((ext_vector_type(4)));

#define LN_EPS 1e-5f

__device__ __forceinline__ void gl2lds16(const void* g, void* l) {
  __builtin_amdgcn_global_load_lds((const __attribute__((address_space(1))) uint32_t*)g,
                                   (__attribute__((address_space(3))) uint32_t*)l, 16, 0, 0);
}

// ---------------- K1: LN rows for emb_prompt (rows 0..255) and emb_column (256..511)
__global__ __launch_bounds__(256) void k_ln_rows(
    const float* __restrict__ emb_prompt, const float* __restrict__ lnp_w, const float* __restrict__ lnp_b,
    const float* __restrict__ emb_column, const float* __restrict__ lnc_w, const float* __restrict__ lnc_b,
    float* __restrict__ out_prompt, float* __restrict__ out_col)
{
  int row = blockIdx.x * 4 + (threadIdx.x >> 6);
  int lane = threadIdx.x & 63;
  const float *src, *wp, *bp; float* dst; int r;
  if (row < 256) { src = emb_prompt; wp = lnp_w; bp = lnp_b; dst = out_prompt; r = row; }
  else           { src = emb_column; wp = lnc_w; bp = lnc_b; dst = out_col;    r = row - 256; }
  float4 v = ((const float4*)src)[r * 64 + lane];
  float s1 = v.x + v.y + v.z + v.w;
  float s2 = v.x*v.x + v.y*v.y + v.z*v.z + v.w*v.w;
  #pragma unroll
  for (int o = 32; o > 0; o >>= 1) { s1 += __shfl_xor(s1, o); s2 += __shfl_xor(s2, o); }
  float mu  = s1 * (1.0f/256.0f);
  float var = s2 * (1.0f/256.0f) - mu*mu;
  float rs  = rsqrtf(var + LN_EPS);
  float4 w4 = ((const float4*)wp)[lane];
  float4 b4 = ((const float4*)bp)[lane];
  float4 y;
  y.x = (v.x-mu)*rs*w4.x + b4.x;
  y.y = (v.y-mu)*rs*w4.y + b4.y;
  y.z = (v.z-mu)*rs*w4.z + b4.z;
  y.w = (v.w-mu)*rs*w4.w + b4.w;
  ((float4*)dst)[r * 64 + lane] = y;
}

// ---------------- K2: x_prompt = [LN(emb_prompt) | prev] @ W^T + b + emb_prompt  (4 p per block)
__global__ __launch_bounds__(256) void k_xprompt(
    const float* __restrict__ ln_prompt, const float* __restrict__ prev,
    const float* __restrict__ W, const float* __restrict__ bias,
    const float* __restrict__ emb_prompt, float* __restrict__ xprompt)
{
  __shared__ float xp[4][512];
  int t = threadIdx.x;
  int pb = blockIdx.x * 4;
  #pragma unroll
  for (int r = 0; r < 4; ++r) {
    xp[r][t]       = ln_prompt[(pb+r)*256 + t];
    xp[r][256 + t] = prev[(pb+r)*256 + t];
  }
  __syncthreads();
  float acc[4] = {0.f, 0.f, 0.f, 0.f};
  const float4* W4 = (const float4*)(W + (size_t)t * 512);
  for (int k4 = 0; k4 < 128; ++k4) {
    float4 wv = W4[k4];
    #pragma unroll
    for (int r = 0; r < 4; ++r) {
      float4 xq = ((const float4*)xp[r])[k4];
      acc[r] += wv.x*xq.x + wv.y*xq.y + wv.z*xq.z + wv.w*xq.w;
    }
  }
  float bb = bias[t];
  #pragma unroll
  for (int r = 0; r < 4; ++r)
    xprompt[(pb+r)*256 + t] = acc[r] + bb + emb_prompt[(pb+r)*256 + t];
}

// ---------------- K3: mask = softmax(x_prompt @ x_col^T) (4 p per block), fp32 + fp16
__global__ __launch_bounds__(256) void k_mask(
    const float* __restrict__ xprompt, const float* __restrict__ xcol,
    float* __restrict__ mask_f32, _Float16* __restrict__ mask_f16)
{
  __shared__ float xp[4][256];
  __shared__ float4 wred[4];
  __shared__ float4 wred2[4];
  int t = threadIdx.x, w = t >> 6, lane = t & 63;
  int pb = blockIdx.x * 4;
  #pragma unroll
  for (int r = 0; r < 4; ++r) xp[r][t] = xprompt[(pb+r)*256 + t];
  __syncthreads();
  float sc[4] = {0.f, 0.f, 0.f, 0.f};
  const float4* c4 = (const float4*)(xcol + (size_t)t * 256);
  for (int d4 = 0; d4 < 64; ++d4) {
    float4 cv = c4[d4];
    #pragma unroll
    for (int r = 0; r < 4; ++r) {
      float4 xq = ((const float4*)xp[r])[d4];
      sc[r] += cv.x*xq.x + cv.y*xq.y + cv.z*xq.z + cv.w*xq.w;
    }
  }
  float m[4] = {sc[0], sc[1], sc[2], sc[3]};
  #pragma unroll
  for (int o = 32; o > 0; o >>= 1) {
    #pragma unroll
    for (int r = 0; r < 4; ++r) m[r] = fmaxf(m[r], __shfl_xor(m[r], o));
  }
  if (lane == 0) wred[w] = make_float4(m[0], m[1], m[2], m[3]);
  __syncthreads();
  float4 a0 = wred[0], a1 = wred[1], a2 = wred[2], a3 = wred[3];
  float M[4] = { fmaxf(fmaxf(a0.x,a1.x), fmaxf(a2.x,a3.x)),
                 fmaxf(fmaxf(a0.y,a1.y), fmaxf(a2.y,a3.y)),
                 fmaxf(fmaxf(a0.z,a1.z), fmaxf(a2.z,a3.z)),
                 fmaxf(fmaxf(a0.w,a1.w), fmaxf(a2.w,a3.w)) };
  float e[4], s[4];
  #pragma unroll
  for (int r = 0; r < 4; ++r) { e[r] = expf(sc[r] - M[r]); s[r] = e[r]; }
  #pragma unroll
  for (int o = 32; o > 0; o >>= 1) {
    #pragma unroll
    for (int r = 0; r < 4; ++r) s[r] += __shfl_xor(s[r], o);
  }
  if (lane == 0) wred2[w] = make_float4(s[0], s[1], s[2], s[3]);
  __syncthreads();
  float4 b0 = wred2[0], b1 = wred2[1], b2 = wred2[2], b3 = wred2[3];
  float S[4] = { b0.x+b1.x+b2.x+b3.x, b0.y+b1.y+b2.y+b3.y,
                 b0.z+b1.z+b2.z+b3.z, b0.w+b1.w+b2.w+b3.w };
  #pragma unroll
  for (int r = 0; r < 4; ++r) {
    float mv = e[r] / S[r];
    mask_f32[(pb+r)*256 + t] = mv;
    mask_f16[(pb+r)*256 + t] = (_Float16)mv;
  }
}

// ---------------- K4: x_emb = LN(relu(feb + x*few)) -> fp16, blocked layout [c/8][b*256+d][c%8]
__global__ __launch_bounds__(256) void k_xemb(
    const float* __restrict__ x, const float* __restrict__ few, const float* __restrict__ feb,
    const float* __restrict__ lnw, const float* __restrict__ lnb, _Float16* __restrict__ emb)
{
  __shared__ float ldsv[8][256];
  __shared__ float stat_mu[8], stat_rs[8];
  int t = threadIdx.x, w = t >> 6, lane = t & 63;
  int b = blockIdx.x >> 5, cg = blockIdx.x & 31;
  float v[8];
  #pragma unroll
  for (int cl = 0; cl < 8; ++cl) {
    int c = cg*8 + cl;
    float xv = x[b*256 + c];
    float val = feb[c*256 + t] + xv * few[c*256 + t];
    v[cl] = fmaxf(val, 0.f);
    ldsv[cl][t] = v[cl];
  }
  __syncthreads();
  #pragma unroll
  for (int j = 0; j < 2; ++j) {
    int cl = w*2 + j;
    float4 a = ((const float4*)ldsv[cl])[lane];
    float s1 = a.x + a.y + a.z + a.w;
    float s2 = a.x*a.x + a.y*a.y + a.z*a.z + a.w*a.w;
    #pragma unroll
    for (int o = 32; o > 0; o >>= 1) { s1 += __shfl_xor(s1, o); s2 += __shfl_xor(s2, o); }
    if (lane == 0) {
      float mu  = s1 * (1.0f/256.0f);
      float var = s2 * (1.0f/256.0f) - mu*mu;
      stat_mu[cl] = mu;
      stat_rs[cl] = rsqrtf(var + LN_EPS);
    }
  }
  __syncthreads();
  float lw = lnw[t], lb = lnb[t];
  half8 h;
  #pragma unroll
  for (int cl = 0; cl < 8; ++cl)
    h[cl] = (_Float16)((v[cl] - stat_mu[cl]) * stat_rs[cl] * lw + lb);
  ((uint4*)emb)[(size_t)cg*65536 + (size_t)b*256 + t] = *(const uint4*)&h;
}

// ---------------- K5: out[b,p,d] = (1+ew[p]) * sum_c mask[p,c]*emb[c,(b,d)] + mask[b,p]*eb[b]
// Single GEMM: M=256 (p), N=65536 (b*256+d), K=256 (c). 128x128 tile, BK=64, fp16 MFMA.
__global__ __launch_bounds__(256) void k_gemm(
    const _Float16* __restrict__ Bmat,   // emb, [c/8][n][c%8]
    const _Float16* __restrict__ Amask,  // mask fp16 [p][c]
    const float* __restrict__ mask_f32,
    const float* __restrict__ ew, const float* __restrict__ eb,
    float* __restrict__ out)
{
  __shared__ __align__(16) _Float16 As[128 * 72];      // padded [m][72]
  __shared__ __align__(16) _Float16 Bs[8 * 128 * 8];   // [k8][n][8]
  int t = threadIdx.x, w = t >> 6, lane = t & 63;
  int lm = lane & 15, quad = lane >> 4;
  int wm = (w & 1) * 64, wn = (w >> 1) * 64;
  int p0 = blockIdx.x * 128;
  int n0 = blockIdx.y * 128;

  f32x4 acc[4][4];
  #pragma unroll
  for (int i = 0; i < 4; ++i)
    #pragma unroll
    for (int j = 0; j < 4; ++j)
      acc[i][j] = (f32x4){0.f, 0.f, 0.f, 0.f};

  for (int kb = 0; kb < 4; ++kb) {
    int k0 = kb * 64;
    if (kb) __syncthreads();
    // B tile: 1024 x 16B units via global_load_lds (wave-uniform base + lane*16)
    #pragma unroll
    for (int i = 0; i < 4; ++i) {
      int u = i*256 + t;
      int chi = u >> 7, np = u & 127;
      gl2lds16(Bmat + (size_t)(kb*8 + chi)*524288 + (size_t)(n0 + np)*8, Bs + (size_t)u*8);
    }
    // A tile via VGPR into padded LDS
    uint4 av[4];
    #pragma unroll
    for (int i = 0; i < 4; ++i) {
      int u = i*256 + t;
      int m = u >> 3, k8 = u & 7;
      av[i] = *(const uint4*)(Amask + (size_t)(p0 + m)*256 + k0 + k8*8);
    }
    #pragma unroll
    for (int i = 0; i < 4; ++i) {
      int u = i*256 + t;
      int m = u >> 3, k8 = u & 7;
      *(uint4*)(As + m*72 + k8*8) = av[i];
    }
    __syncthreads();
    #pragma unroll
    for (int ks = 0; ks < 2; ++ks) {
      half8 af[4], bf[4];
      #pragma unroll
      for (int mt = 0; mt < 4; ++mt)
        af[mt] = *(const half8*)(As + (wm + mt*16 + lm)*72 + ks*32 + quad*8);
      #pragma unroll
      for (int nt = 0; nt < 4; ++nt)
        bf[nt] = *(const half8*)(Bs + ((ks*4 + quad)*128 + wn + nt*16 + lm)*8);
      #pragma unroll
      for (int mt = 0; mt < 4; ++mt)
        #pragma unroll
        for (int nt = 0; nt < 4; ++nt)
          acc[mt][nt] = __builtin_amdgcn_mfma_f32_16x16x32_f16(af[mt], bf[nt], acc[mt][nt], 0, 0, 0);
    }
  }

  // epilogue: C/D layout col=lane&15, row=quad*4+reg
  int b = n0 >> 8;
  float ebv = eb[b];
  #pragma unroll
  for (int mt = 0; mt < 4; ++mt) {
    float sp[4], tb[4];
    #pragma unroll
    for (int r = 0; r < 4; ++r) {
      int p = p0 + wm + mt*16 + quad*4 + r;
      sp[r] = 1.0f + ew[p];
      tb[r] = mask_f32[b*256 + p] * ebv;
    }
    #pragma unroll
    for (int nt = 0; nt < 4; ++nt) {
      int d = (n0 & 255) + wn + nt*16 + lm;
      #pragma unroll
      for (int r = 0; r < 4; ++r) {
        int p = p0 + wm + mt*16 + quad*4 + r;
        out[((size_t)b << 16) + ((size_t)p << 8) + d] = acc[mt][nt][r] * sp[r] + tb[r];
      }
    }
  }
}

extern "C" void kernel_launch(void* const* d_in, const int* in_sizes, int n_in,
                              void* d_out, int out_size, void* d_ws, size_t ws_size,
                              hipStream_t stream) {
  const float* x        = (const float*)d_in[0];
  const float* prev     = (const float*)d_in[1];
  const float* few      = (const float*)d_in[2];
  const float* feb      = (const float*)d_in[3];
  const float* ln_emb_w = (const float*)d_in[4];
  const float* ln_emb_b = (const float*)d_in[5];
  const float* ln_col_w = (const float*)d_in[6];
  const float* ln_col_b = (const float*)d_in[7];
  const float* ln_pr_w  = (const float*)d_in[8];
  const float* ln_pr_b  = (const float*)d_in[9];
  const float* dimp_w   = (const float*)d_in[10];
  const float* dimp_b   = (const float*)d_in[11];
  const float* emb_col  = (const float*)d_in[12];
  const float* emb_pr   = (const float*)d_in[13];
  const float* ew       = (const float*)d_in[14];
  const float* eb       = (const float*)d_in[15];
  float* out = (float*)d_out;

  char* wsb = (char*)d_ws;
  _Float16* ws_emb    = (_Float16*)(wsb);                // 33,554,432 B
  float*    ws_mask   = (float*)(wsb + 33554432);        //    262,144 B
  _Float16* ws_mask_h = (_Float16*)(wsb + 33816576);     //    131,072 B
  float*    ws_lnp    = (float*)(wsb + 33947648);        //    262,144 B
  float*    ws_xcol   = (float*)(wsb + 34209792);        //    262,144 B
  float*    ws_xp     = (float*)(wsb + 34471936);        //    262,144 B

  k_ln_rows<<<dim3(128), dim3(256), 0, stream>>>(emb_pr, ln_pr_w, ln_pr_b,
                                                 emb_col, ln_col_w, ln_col_b,
                                                 ws_lnp, ws_xcol);
  k_xprompt<<<dim3(64), dim3(256), 0, stream>>>(ws_lnp, prev, dimp_w, dimp_b, emb_pr, ws_xp);
  k_mask<<<dim3(64), dim3(256), 0, stream>>>(ws_xp, ws_xcol, ws_mask, ws_mask_h);
  k_xemb<<<dim3(8192), dim3(256), 0, stream>>>(x, few, feb, ln_emb_w, ln_emb_b, ws_emb);
  k_gemm<<<dim3(2, 512), dim3(256), 0, stream>>>(ws_emb, ws_mask_h, ws_mask, ew, eb, out);
}